// Round 1
// 410.349 us; speedup vs baseline: 1.0098x; 1.0098x over previous
//
#include <hip/hip_runtime.h>

typedef short  bf16x8 __attribute__((ext_vector_type(8)));
typedef float  f32x4  __attribute__((ext_vector_type(4)));

__device__ __forceinline__ unsigned short f2bf(float x) {
    unsigned int u = __float_as_uint(x);
    u += 0x7FFFu + ((u >> 16) & 1u);   // round-to-nearest-even
    return (unsigned short)(u >> 16);
}
__device__ __forceinline__ unsigned int pack2(float lo, float hi) {
    return (unsigned int)f2bf(lo) | ((unsigned int)f2bf(hi) << 16);
}

// ---------------- bf16 MFMA GEMM, 128x128 tile, K=256 -------------------------
// A: fp32 (A_F32, guarded to M rows, lda floats) or bf16 (padded ws, lda shorts).
// Bt: bf16 [Nn][256] (B transposed). C: bf16 arena (ldc) or fp32 (guarded, ldc).
// EPI: 0=none, 2=+bias, 3=relu(+bias) for gn<256 only (fused MLP1+conv1 weights).
template<bool A_F32, bool OUT_BF16, int EPI>
__global__ __launch_bounds__(256)
void gemm_mfma(const void* __restrict__ Av, const unsigned short* __restrict__ Bt,
               const float* __restrict__ bias, void* __restrict__ Cout,
               int M, int Nn, int lda, int ldc, int coff)
{
    constexpr int K = 256, BK = 32, ROWP = 40;  // 80B LDS row stride (conflict-free, measured R3)
    __shared__ unsigned short As[128 * ROWP];
    __shared__ unsigned short Bs[128 * ROWP];

    const int tid = threadIdx.x;
    const int lane = tid & 63, wid = tid >> 6;
    const int wm = wid & 1, wn = wid >> 1;      // 2x2 waves, each 64x64
    const int l15 = lane & 15, lq = lane >> 4;
    const int mBase = blockIdx.x * 128, nBase = blockIdx.y * 128;

    f32x4 acc[4][4];
#pragma unroll
    for (int mt = 0; mt < 4; ++mt)
#pragma unroll
        for (int nt = 0; nt < 4; ++nt)
            acc[mt][nt] = (f32x4){0.f, 0.f, 0.f, 0.f};

    const int srow = tid >> 1;          // 0..127
    const int sseg = (tid & 1) * 16;    // 0 / 16 shorts

    for (int k0 = 0; k0 < K; k0 += BK) {
        if (A_F32) {
            const float* Af = (const float*)Av;
            const int gm = mBase + srow;
            float4 f0, f1, f2, f3;
            if (gm < M) {
                const float4* p = (const float4*)&Af[(size_t)gm * lda + k0 + sseg];
                f0 = p[0]; f1 = p[1]; f2 = p[2]; f3 = p[3];
            } else {
                f0 = f1 = f2 = f3 = make_float4(0.f, 0.f, 0.f, 0.f);
            }
            uint4 o0, o1;
            o0.x = pack2(f0.x, f0.y); o0.y = pack2(f0.z, f0.w);
            o0.z = pack2(f1.x, f1.y); o0.w = pack2(f1.z, f1.w);
            o1.x = pack2(f2.x, f2.y); o1.y = pack2(f2.z, f2.w);
            o1.z = pack2(f3.x, f3.y); o1.w = pack2(f3.z, f3.w);
            *(uint4*)&As[srow * ROWP + sseg]     = o0;
            *(uint4*)&As[srow * ROWP + sseg + 8] = o1;
        } else {
            const unsigned short* Ab = (const unsigned short*)Av;
            const uint4* p = (const uint4*)&Ab[(size_t)(mBase + srow) * lda + k0 + sseg];
            *(uint4*)&As[srow * ROWP + sseg]     = p[0];
            *(uint4*)&As[srow * ROWP + sseg + 8] = p[1];
        }
        {
            const uint4* q = (const uint4*)&Bt[(size_t)(nBase + srow) * 256 + k0 + sseg];
            *(uint4*)&Bs[srow * ROWP + sseg]     = q[0];
            *(uint4*)&Bs[srow * ROWP + sseg + 8] = q[1];
        }
        __syncthreads();

        bf16x8 af[4], bfr[4];
#pragma unroll
        for (int mt = 0; mt < 4; ++mt)
            af[mt] = *(const bf16x8*)&As[(wm * 64 + mt * 16 + l15) * ROWP + lq * 8];
#pragma unroll
        for (int nt = 0; nt < 4; ++nt)
            bfr[nt] = *(const bf16x8*)&Bs[(wn * 64 + nt * 16 + l15) * ROWP + lq * 8];
#pragma unroll
        for (int mt = 0; mt < 4; ++mt)
#pragma unroll
            for (int nt = 0; nt < 4; ++nt)
                acc[mt][nt] = __builtin_amdgcn_mfma_f32_16x16x32_bf16(
                    af[mt], bfr[nt], acc[mt][nt], 0, 0, 0);
        __syncthreads();
    }

#pragma unroll
    for (int mt = 0; mt < 4; ++mt) {
#pragma unroll
        for (int nt = 0; nt < 4; ++nt) {
            const int gn = nBase + wn * 64 + nt * 16 + l15;
#pragma unroll
            for (int i = 0; i < 4; ++i) {
                const int gm = mBase + wm * 64 + mt * 16 + lq * 4 + i;
                float v = acc[mt][nt][i];
                if (EPI == 2) v += bias[gn];
                if (EPI == 3) { if (gn < 256) v = fmaxf(v + bias[gn], 0.f); }
                if (OUT_BF16) {
                    ((unsigned short*)Cout)[(size_t)gm * ldc + coff + gn] = f2bf(v);
                } else {
                    if (gm < M)
                        ((float*)Cout)[(size_t)gm * ldc + coff + gn] = v;
                }
            }
        }
    }
}

// ---------------- setup: weight transpose-convert + rowptr zero ---------------
// warena rows: [0,256)=mw1^T, [256,512)=W1^T, [512,640)=mw2^T, [640,768)=W2^T
__global__ __launch_bounds__(256)
void setup_kernel(const float* __restrict__ mw1, const float* __restrict__ W1,
                  const float* __restrict__ mw2, const float* __restrict__ W2,
                  unsigned short* __restrict__ warena, int* __restrict__ rowptr, int n1)
{
    int i = blockIdx.x * 256 + threadIdx.x;
    if (i < n1) rowptr[i] = 0;
    if (i >= 768 * 256) return;
    int r = i >> 8, k = i & 255;
    float v;
    if (r < 256)      v = mw1[k * 256 + r];
    else if (r < 512) v = W1[k * 256 + (r - 256)];
    else if (r < 640) v = mw2[k * 128 + (r - 512)];
    else              v = W2[k * 128 + (r - 640)];
    warena[i] = f2bf(v);
}

// ---------------- X fp32 -> bf16 conversion (padded to Mp rows) ---------------
__global__ __launch_bounds__(256)
void xconv_kernel(const float* __restrict__ X, unsigned short* __restrict__ Xb,
                  int N, int Mp)
{
    int i = blockIdx.x * 256 + threadIdx.x;   // one thread per 8 elements
    if (i >= Mp * 32) return;
    int row = i >> 5, seg = (i & 31) << 3;
    uint4 o;
    if (row < N) {
        const float4* p = (const float4*)&X[(size_t)row * 256 + seg];
        float4 f0 = p[0], f1 = p[1];
        o.x = pack2(f0.x, f0.y); o.y = pack2(f0.z, f0.w);
        o.z = pack2(f1.x, f1.y); o.w = pack2(f1.z, f1.w);
    } else {
        o = make_uint4(0u, 0u, 0u, 0u);
    }
    *(uint4*)&Xb[(size_t)row * 256 + seg] = o;
}

// ---------------- CSR build ---------------------------------------------------
__global__ __launch_bounds__(256)
void hist_kernel(const int* __restrict__ dst, int* __restrict__ cnt, int E)
{
    int e = blockIdx.x * 256 + threadIdx.x;
    if (e < E) atomicAdd(&cnt[dst[e]], 1);
}

__global__ __launch_bounds__(256)
void reduce_chunks(const int* __restrict__ cnt, int* __restrict__ bsum, int n)
{
    __shared__ int s[256];
    int i = blockIdx.x * 256 + threadIdx.x;
    s[threadIdx.x] = (i < n) ? cnt[i] : 0;
    __syncthreads();
    for (int o = 128; o > 0; o >>= 1) {
        if (threadIdx.x < o) s[threadIdx.x] += s[threadIdx.x + o];
        __syncthreads();
    }
    if (threadIdx.x == 0) bsum[blockIdx.x] = s[0];
}

__global__ __launch_bounds__(256)
void scan_bsum(int* __restrict__ bsum, int nb, int* __restrict__ rowptr, int n)
{
    __shared__ int s[256];
    int t = threadIdx.x;
    int v = (t < nb) ? bsum[t] : 0;
    s[t] = v;
    __syncthreads();
    for (int o = 1; o < 256; o <<= 1) {
        int u = (t >= o) ? s[t - o] : 0;
        __syncthreads();
        s[t] += u;
        __syncthreads();
    }
    if (t < nb) bsum[t] = s[t] - v;
    if (t == 255) rowptr[n] = s[255];
}

__global__ __launch_bounds__(256)
void scan_write(const int* cnt, const int* __restrict__ bsum,
                int* rowptr, int* __restrict__ pos, int n)
{
    __shared__ int s[256];
    int t = threadIdx.x;
    int i = blockIdx.x * 256 + t;
    int v = (i < n) ? cnt[i] : 0;
    s[t] = v;
    __syncthreads();
    for (int o = 1; o < 256; o <<= 1) {
        int u = (t >= o) ? s[t - o] : 0;
        __syncthreads();
        s[t] += u;
        __syncthreads();
    }
    if (i < n) {
        int ex = bsum[blockIdx.x] + s[t] - v;
        rowptr[i] = ex;
        pos[i] = ex;
    }
}

__global__ __launch_bounds__(256)
void scatter_kernel(const int* __restrict__ src, const int* __restrict__ dst,
                    const float* __restrict__ w, int* __restrict__ pos,
                    int2* __restrict__ packed, int E)
{
    int e = blockIdx.x * 256 + threadIdx.x;
    if (e >= E) return;
    int p = atomicAdd(&pos[dst[e]], 1);
    packed[p] = make_int2(src[e], __float_as_int(w[e]));
}

// ---------------- gather SpMM over bf16 rows, 4-way edge unroll ---------------
// x row stride ldx shorts; TPR lanes/row, 8 feats/lane. fp32 out slice (ldo,coff);
// optional bf16 copy at stride ldd. 4 gathers in flight per row group (latency
// hiding); folds into 2 accumulator banks to limit VGPR.
template<int TPR, bool RELU, bool DUAL>
__global__ __launch_bounds__(256)
void spmm_csr_bf16(const unsigned short* __restrict__ x,
                   const int* __restrict__ rowptr, const int2* __restrict__ packed,
                   float* __restrict__ outf, unsigned short* __restrict__ outb,
                   int N, int ldx, int ldo, int coff, int ldd)
{
    const int rpb = 256 / TPR;
    const int r = blockIdx.x * rpb + threadIdx.x / TPR;
    const int lane = threadIdx.x % TPR;
    if (r >= N) return;
    const int beg = rowptr[r], end = rowptr[r + 1];
    const unsigned short* xp = x + lane * 8;
    float a0[8] = {0, 0, 0, 0, 0, 0, 0, 0};
    float a1[8] = {0, 0, 0, 0, 0, 0, 0, 0};
    int i = beg;
    for (; i + 3 < end; i += 4) {
        int2 e0 = packed[i], e1 = packed[i + 1], e2 = packed[i + 2], e3 = packed[i + 3];
        uint4 v0 = *(const uint4*)&xp[(size_t)e0.x * ldx];
        uint4 v1 = *(const uint4*)&xp[(size_t)e1.x * ldx];
        uint4 v2 = *(const uint4*)&xp[(size_t)e2.x * ldx];
        uint4 v3 = *(const uint4*)&xp[(size_t)e3.x * ldx];
        float w0 = __int_as_float(e0.y), w1 = __int_as_float(e1.y);
        float w2 = __int_as_float(e2.y), w3 = __int_as_float(e3.y);
        unsigned int s0[4] = {v0.x, v0.y, v0.z, v0.w};
        unsigned int s1[4] = {v1.x, v1.y, v1.z, v1.w};
        unsigned int s2[4] = {v2.x, v2.y, v2.z, v2.w};
        unsigned int s3[4] = {v3.x, v3.y, v3.z, v3.w};
#pragma unroll
        for (int j = 0; j < 4; ++j) {
            a0[2 * j]     = fmaf(w0, __uint_as_float(s0[j] << 16),         a0[2 * j]);
            a0[2 * j + 1] = fmaf(w0, __uint_as_float(s0[j] & 0xFFFF0000u), a0[2 * j + 1]);
            a1[2 * j]     = fmaf(w1, __uint_as_float(s1[j] << 16),         a1[2 * j]);
            a1[2 * j + 1] = fmaf(w1, __uint_as_float(s1[j] & 0xFFFF0000u), a1[2 * j + 1]);
            a0[2 * j]     = fmaf(w2, __uint_as_float(s2[j] << 16),         a0[2 * j]);
            a0[2 * j + 1] = fmaf(w2, __uint_as_float(s2[j] & 0xFFFF0000u), a0[2 * j + 1]);
            a1[2 * j]     = fmaf(w3, __uint_as_float(s3[j] << 16),         a1[2 * j]);
            a1[2 * j + 1] = fmaf(w3, __uint_as_float(s3[j] & 0xFFFF0000u), a1[2 * j + 1]);
        }
    }
    for (; i + 1 < end; i += 2) {   // runs at most once (<=3 edges left)
        int2 e0 = packed[i], e1 = packed[i + 1];
        uint4 v0 = *(const uint4*)&xp[(size_t)e0.x * ldx];
        uint4 v1 = *(const uint4*)&xp[(size_t)e1.x * ldx];
        float w0 = __int_as_float(e0.y), w1 = __int_as_float(e1.y);
        unsigned int s0[4] = {v0.x, v0.y, v0.z, v0.w};
        unsigned int s1[4] = {v1.x, v1.y, v1.z, v1.w};
#pragma unroll
        for (int j = 0; j < 4; ++j) {
            a0[2 * j]     = fmaf(w0, __uint_as_float(s0[j] << 16),         a0[2 * j]);
            a0[2 * j + 1] = fmaf(w0, __uint_as_float(s0[j] & 0xFFFF0000u), a0[2 * j + 1]);
            a1[2 * j]     = fmaf(w1, __uint_as_float(s1[j] << 16),         a1[2 * j]);
            a1[2 * j + 1] = fmaf(w1, __uint_as_float(s1[j] & 0xFFFF0000u), a1[2 * j + 1]);
        }
    }
    if (i < end) {
        int2 e0 = packed[i];
        uint4 v0 = *(const uint4*)&xp[(size_t)e0.x * ldx];
        float w0 = __int_as_float(e0.y);
        unsigned int s0[4] = {v0.x, v0.y, v0.z, v0.w};
#pragma unroll
        for (int j = 0; j < 4; ++j) {
            a0[2 * j]     = fmaf(w0, __uint_as_float(s0[j] << 16),         a0[2 * j]);
            a0[2 * j + 1] = fmaf(w0, __uint_as_float(s0[j] & 0xFFFF0000u), a0[2 * j + 1]);
        }
    }
    float acc[8];
#pragma unroll
    for (int j = 0; j < 8; ++j) {
        acc[j] = a0[j] + a1[j];
        if (RELU) acc[j] = fmaxf(acc[j], 0.f);
    }
    float* o = &outf[(size_t)r * ldo + coff + lane * 8];
    *(float4*)o       = make_float4(acc[0], acc[1], acc[2], acc[3]);
    *(float4*)(o + 4) = make_float4(acc[4], acc[5], acc[6], acc[7]);
    if (DUAL) {
        uint4 p;
        p.x = pack2(acc[0], acc[1]); p.y = pack2(acc[2], acc[3]);
        p.z = pack2(acc[4], acc[5]); p.w = pack2(acc[6], acc[7]);
        *(uint4*)&outb[(size_t)r * ldd + lane * 8] = p;
    }
}

// ---------------- launch ------------------------------------------------------
extern "C" void kernel_launch(void* const* d_in, const int* in_sizes, int n_in,
                              void* d_out, int out_size, void* d_ws, size_t ws_size,
                              hipStream_t stream)
{
    const float* X    = (const float*)d_in[0];
    const int*   esrc = (const int*)  d_in[1];
    const int*   edst = (const int*)  d_in[2];
    const float* ew   = (const float*)d_in[3];
    const float* W1   = (const float*)d_in[4];
    const float* W2   = (const float*)d_in[5];
    const float* mw1  = (const float*)d_in[6];
    const float* mb1  = (const float*)d_in[7];
    const float* mw2  = (const float*)d_in[8];
    const float* mb2  = (const float*)d_in[9];

    const int IN_F = 256, HID_F = 256, OUT_F = 128;
    const int N  = in_sizes[0] / IN_F;
    const int E  = in_sizes[1];
    const int LD = OUT_F + HID_F + OUT_F;       // 512
    const int Mp = (N + 127) & ~127;

    float* out = (float*)d_out;

    // workspace (shorts)
    unsigned short* S1Y1  = (unsigned short*)d_ws;          // [Mp][512]: S1 | Y1
    unsigned short* h1b   = S1Y1 + (size_t)Mp * 512;        // [Mp][256] (doubles as Xbf16 before SpMM1)
    unsigned short* gb    = h1b  + (size_t)Mp * 256;        // [Mp][128]
    unsigned short* warena = gb  + (size_t)Mp * 128;        // [768][256]
    unsigned short* Wc   = warena;                          // [512][256]
    unsigned short* mw2t = warena + 512 * 256;              // [128][256]
    unsigned short* w2t  = warena + 640 * 256;              // [128][256]
    int* rowptr = (int*)(warena + 768 * 256);               // N+1
    int* bsum   = rowptr + (((N + 1) + 3) & ~3);            // 256
    int* pos    = bsum + 256;                               // N
    int2* packed = (int2*)(pos + ((N + 1) & ~1));           // E

    unsigned short* Xb = h1b;   // X bf16 lives in h1b slot until SpMM1 overwrites it

    dim3 blk(256);
    const int nb = (N + 255) / 256;
    const int mT = Mp / 128;

    // setup: weight conversion + rowptr zeroing (one kernel)
    setup_kernel<<<768, blk, 0, stream>>>(mw1, W1, mw2, W2, warena, rowptr, N + 1);

    // X fp32 -> bf16 (padded rows zeroed); independent of CSR build
    xconv_kernel<<<Mp / 8, blk, 0, stream>>>(X, Xb, N, Mp);

    // CSR build
    hist_kernel<<<(E + 255) / 256, blk, 0, stream>>>(edst, rowptr, E);
    reduce_chunks<<<nb, blk, 0, stream>>>(rowptr, bsum, N);
    scan_bsum<<<1, blk, 0, stream>>>(bsum, nb, rowptr, N);
    scan_write<<<nb, blk, 0, stream>>>(rowptr, bsum, rowptr, pos, N);
    scatter_kernel<<<(E + 255) / 256, blk, 0, stream>>>(esrc, edst, ew, pos, packed, E);

    // gemmA: [S1 | Y1] = X @ [mw1 | W1]  (relu+b1 on first 256 cols) -> bf16
    // A now pre-converted bf16 (halves A re-fetch across the 4 column blocks,
    // removes pack2 VALU from the staging path)
    gemm_mfma<false, true, 3><<<dim3(mT, 4), blk, 0, stream>>>(
        Xb, Wc, mb1, S1Y1, N, 512, IN_F, 512, 0);

    // K2: out[:,0:128] = S1 @ mw2 + b2 (fp32)
    gemm_mfma<false, false, 2><<<dim3(mT, 1), blk, 0, stream>>>(
        S1Y1, mw2t, mb2, out, N, OUT_F, 512, LD, 0);

    // SpMM1: h1 = relu(A @ Y1) -> out[:,128:384] fp32 + h1b bf16
    spmm_csr_bf16<32, true, true><<<(N + 7) / 8, blk, 0, stream>>>(
        S1Y1 + 256, rowptr, packed, out, h1b, N, 512, LD, OUT_F, 256);

    // K4: gb = h1 @ W2 (bf16)
    gemm_mfma<false, true, 0><<<dim3(mT, 1), blk, 0, stream>>>(
        h1b, w2t, nullptr, gb, N, OUT_F, 256, 128, 0);

    // SpMM2: out[:,384:512] = A @ g (fp32)
    spmm_csr_bf16<16, false, false><<<(N + 15) / 16, blk, 0, stream>>>(
        gb, rowptr, packed, out, nullptr, N, 128, LD, OUT_F + HID_F, 0);
}

// Round 2
// 389.702 us; speedup vs baseline: 1.0633x; 1.0530x over previous
//
#include <hip/hip_runtime.h>

typedef short  bf16x8 __attribute__((ext_vector_type(8)));
typedef float  f32x4  __attribute__((ext_vector_type(4)));

__device__ __forceinline__ unsigned short f2bf(float x) {
    unsigned int u = __float_as_uint(x);
    u += 0x7FFFu + ((u >> 16) & 1u);   // round-to-nearest-even
    return (unsigned short)(u >> 16);
}
__device__ __forceinline__ unsigned int pack2(float lo, float hi) {
    return (unsigned int)f2bf(lo) | ((unsigned int)f2bf(hi) << 16);
}

// ---------------- bf16 MFMA GEMM body, 128x128 tile, K=256 --------------------
// A: fp32 (A_F32, guarded to M rows, lda floats) or bf16 (padded ws, lda shorts).
// Bt: bf16 [*][256] (B transposed). C: bf16 arena (ldc) or fp32 (guarded, ldc).
// EPI: 0=none, 2=+bias, 3=relu(+bias) for gn<256 only.
template<bool A_F32, bool OUT_BF16, int EPI>
__device__ __forceinline__
void gemm_body(const void* __restrict__ Av, const unsigned short* __restrict__ Bt,
               const float* __restrict__ bias, void* __restrict__ Cout,
               int M, int lda, int ldc, int coff, int mBase, int nBase,
               unsigned short* As, unsigned short* Bs)
{
    constexpr int K = 256, BK = 32, ROWP = 40;  // 80B LDS row stride (conflict-free)
    const int tid = threadIdx.x;
    const int lane = tid & 63, wid = tid >> 6;
    const int wm = wid & 1, wn = wid >> 1;      // 2x2 waves, each 64x64
    const int l15 = lane & 15, lq = lane >> 4;

    f32x4 acc[4][4];
#pragma unroll
    for (int mt = 0; mt < 4; ++mt)
#pragma unroll
        for (int nt = 0; nt < 4; ++nt)
            acc[mt][nt] = (f32x4){0.f, 0.f, 0.f, 0.f};

    const int srow = tid >> 1;          // 0..127
    const int sseg = (tid & 1) * 16;    // 0 / 16 shorts

    for (int k0 = 0; k0 < K; k0 += BK) {
        if (A_F32) {
            const float* Af = (const float*)Av;
            const int gm = mBase + srow;
            float4 f0, f1, f2, f3;
            if (gm < M) {
                const float4* p = (const float4*)&Af[(size_t)gm * lda + k0 + sseg];
                f0 = p[0]; f1 = p[1]; f2 = p[2]; f3 = p[3];
            } else {
                f0 = f1 = f2 = f3 = make_float4(0.f, 0.f, 0.f, 0.f);
            }
            uint4 o0, o1;
            o0.x = pack2(f0.x, f0.y); o0.y = pack2(f0.z, f0.w);
            o0.z = pack2(f1.x, f1.y); o0.w = pack2(f1.z, f1.w);
            o1.x = pack2(f2.x, f2.y); o1.y = pack2(f2.z, f2.w);
            o1.z = pack2(f3.x, f3.y); o1.w = pack2(f3.z, f3.w);
            *(uint4*)&As[srow * ROWP + sseg]     = o0;
            *(uint4*)&As[srow * ROWP + sseg + 8] = o1;
        } else {
            const unsigned short* Ab = (const unsigned short*)Av;
            const uint4* p = (const uint4*)&Ab[(size_t)(mBase + srow) * lda + k0 + sseg];
            *(uint4*)&As[srow * ROWP + sseg]     = p[0];
            *(uint4*)&As[srow * ROWP + sseg + 8] = p[1];
        }
        {
            const uint4* q = (const uint4*)&Bt[(size_t)(nBase + srow) * 256 + k0 + sseg];
            *(uint4*)&Bs[srow * ROWP + sseg]     = q[0];
            *(uint4*)&Bs[srow * ROWP + sseg + 8] = q[1];
        }
        __syncthreads();

        bf16x8 af[4], bfr[4];
#pragma unroll
        for (int mt = 0; mt < 4; ++mt)
            af[mt] = *(const bf16x8*)&As[(wm * 64 + mt * 16 + l15) * ROWP + lq * 8];
#pragma unroll
        for (int nt = 0; nt < 4; ++nt)
            bfr[nt] = *(const bf16x8*)&Bs[(wn * 64 + nt * 16 + l15) * ROWP + lq * 8];
#pragma unroll
        for (int mt = 0; mt < 4; ++mt)
#pragma unroll
            for (int nt = 0; nt < 4; ++nt)
                acc[mt][nt] = __builtin_amdgcn_mfma_f32_16x16x32_bf16(
                    af[mt], bfr[nt], acc[mt][nt], 0, 0, 0);
        __syncthreads();
    }

#pragma unroll
    for (int mt = 0; mt < 4; ++mt) {
#pragma unroll
        for (int nt = 0; nt < 4; ++nt) {
            const int gn = nBase + wn * 64 + nt * 16 + l15;
#pragma unroll
            for (int i = 0; i < 4; ++i) {
                const int gm = mBase + wm * 64 + mt * 16 + lq * 4 + i;
                float v = acc[mt][nt][i];
                if (EPI == 2) v += bias[gn];
                if (EPI == 3) { if (gn < 256) v = fmaxf(v + bias[gn], 0.f); }
                if (OUT_BF16) {
                    ((unsigned short*)Cout)[(size_t)gm * ldc + coff + gn] = f2bf(v);
                } else {
                    if (gm < M)
                        ((float*)Cout)[(size_t)gm * ldc + coff + gn] = v;
                }
            }
        }
    }
}

// ---------------- prep: weight transpose-convert + rowptr zero + X->bf16 ------
// role: bid<768 -> setup; else xconv (one thread per 8 elems, padded rows zeroed)
__global__ __launch_bounds__(256)
void prep_kernel(const float* __restrict__ mw1, const float* __restrict__ W1,
                 const float* __restrict__ mw2, const float* __restrict__ W2,
                 unsigned short* __restrict__ warena, int* __restrict__ rowptr, int n1,
                 const float* __restrict__ X, unsigned short* __restrict__ Xb,
                 int N, int Mp)
{
    const int bid = blockIdx.x;
    if (bid < 768) {
        int i = bid * 256 + threadIdx.x;
        if (i < n1) rowptr[i] = 0;
        int r = i >> 8, k = i & 255;
        float v;
        if (r < 256)      v = mw1[k * 256 + r];
        else if (r < 512) v = W1[k * 256 + (r - 256)];
        else if (r < 640) v = mw2[k * 128 + (r - 512)];
        else              v = W2[k * 128 + (r - 640)];
        warena[i] = f2bf(v);
    } else {
        int j = (bid - 768) * 256 + threadIdx.x;
        if (j >= Mp * 32) return;
        int row = j >> 5, seg = (j & 31) << 3;
        uint4 o;
        if (row < N) {
            const float4* p = (const float4*)&X[(size_t)row * 256 + seg];
            float4 f0 = p[0], f1 = p[1];
            o.x = pack2(f0.x, f0.y); o.y = pack2(f0.z, f0.w);
            o.z = pack2(f1.x, f1.y); o.w = pack2(f1.z, f1.w);
        } else {
            o = make_uint4(0u, 0u, 0u, 0u);
        }
        *(uint4*)&Xb[(size_t)row * 256 + seg] = o;
    }
}

// ---------------- fused gemmA + histogram -------------------------------------
// gemm roles interleaved 1:2 with hist roles so short hist blocks co-reside with
// long GEMM blocks (hist atomics hide under MFMA). Coverage: hist ids [0,2G)
// from r in {1,2}; ids >= 2G from bids >= 3G.
__global__ __launch_bounds__(256)
void gemmA_hist(const unsigned short* __restrict__ Xb,
                const unsigned short* __restrict__ Wc,
                const float* __restrict__ mb1, unsigned short* __restrict__ S1Y1,
                int M, int G,
                const int* __restrict__ dst, int* __restrict__ cnt, int E)
{
    __shared__ unsigned short As[128 * 40];
    __shared__ unsigned short Bs[128 * 40];
    const int bid = blockIdx.x;
    const int r = bid % 3, g = bid / 3;
    if (bid < 3 * G && r == 0) {
        // sibling-adjacent decode: 4 column tiles of one row panel are adjacent
        const int mBase = (g >> 2) * 128, nBase = (g & 3) * 128;
        gemm_body<false, true, 3>(Xb, Wc, mb1, S1Y1, M, 256, 512, 0,
                                  mBase, nBase, As, Bs);
    } else {
        int hid = (bid < 3 * G) ? (2 * g + (r - 1)) : (2 * G + (bid - 3 * G));
        int e = hid * 256 + threadIdx.x;
        if (e < E) atomicAdd(&cnt[dst[e]], 1);
    }
}

// ---------------- fused K2 + scatter ------------------------------------------
// K2 (391 blocks) interleaved 1:8 with scatter (3125 blocks).
__global__ __launch_bounds__(256)
void k2_scatter(const unsigned short* __restrict__ S1Y1,
                const unsigned short* __restrict__ mw2t,
                const float* __restrict__ mb2, float* __restrict__ out,
                int M, int ldc, int G,
                const int* __restrict__ src, const int* __restrict__ dst,
                const float* __restrict__ w, int* __restrict__ pos,
                int2* __restrict__ packed, int E)
{
    __shared__ unsigned short As[128 * 40];
    __shared__ unsigned short Bs[128 * 40];
    const int bid = blockIdx.x;
    const int r = bid % 9, g = bid / 9;
    if (bid < 9 * G && r == 0) {
        gemm_body<false, false, 2>(S1Y1, mw2t, mb2, out, M, 512, ldc, 0,
                                   g * 128, 0, As, Bs);
    } else {
        int sid = (bid < 9 * G) ? (bid - g - 1) : (8 * G + (bid - 9 * G));
        int e = sid * 256 + threadIdx.x;
        if (e >= E) return;
        int p = atomicAdd(&pos[dst[e]], 1);
        packed[p] = make_int2(src[e], __float_as_int(w[e]));
    }
}

// ---------------- K4 standalone (A fp32 from out h1 slice) --------------------
__global__ __launch_bounds__(256)
void gemm_k4(const float* __restrict__ A, const unsigned short* __restrict__ Bt,
             unsigned short* __restrict__ Cout, int M, int lda, int ldc)
{
    __shared__ unsigned short As[128 * 40];
    __shared__ unsigned short Bs[128 * 40];
    gemm_body<true, true, 0>(A, Bt, nullptr, Cout, M, lda, ldc, 0,
                             blockIdx.x * 128, 0, As, Bs);
}

// ---------------- CSR build scans ---------------------------------------------
__global__ __launch_bounds__(256)
void reduce_chunks(const int* __restrict__ cnt, int* __restrict__ bsum, int n)
{
    __shared__ int s[256];
    int i = blockIdx.x * 256 + threadIdx.x;
    s[threadIdx.x] = (i < n) ? cnt[i] : 0;
    __syncthreads();
    for (int o = 128; o > 0; o >>= 1) {
        if (threadIdx.x < o) s[threadIdx.x] += s[threadIdx.x + o];
        __syncthreads();
    }
    if (threadIdx.x == 0) bsum[blockIdx.x] = s[0];
}

__global__ __launch_bounds__(256)
void scan_bsum(int* __restrict__ bsum, int nb, int* __restrict__ rowptr, int n)
{
    __shared__ int s[256];
    int t = threadIdx.x;
    int v = (t < nb) ? bsum[t] : 0;
    s[t] = v;
    __syncthreads();
    for (int o = 1; o < 256; o <<= 1) {
        int u = (t >= o) ? s[t - o] : 0;
        __syncthreads();
        s[t] += u;
        __syncthreads();
    }
    if (t < nb) bsum[t] = s[t] - v;
    if (t == 255) rowptr[n] = s[255];
}

__global__ __launch_bounds__(256)
void scan_write(const int* cnt, const int* __restrict__ bsum,
                int* rowptr, int* __restrict__ pos, int n)
{
    __shared__ int s[256];
    int t = threadIdx.x;
    int i = blockIdx.x * 256 + t;
    int v = (i < n) ? cnt[i] : 0;
    s[t] = v;
    __syncthreads();
    for (int o = 1; o < 256; o <<= 1) {
        int u = (t >= o) ? s[t - o] : 0;
        __syncthreads();
        s[t] += u;
        __syncthreads();
    }
    if (i < n) {
        int ex = bsum[blockIdx.x] + s[t] - v;
        rowptr[i] = ex;
        pos[i] = ex;
    }
}

// ---------------- gather SpMM over bf16 rows, 4-way edge unroll ---------------
template<int TPR, bool RELU, bool DUAL>
__global__ __launch_bounds__(256)
void spmm_csr_bf16(const unsigned short* __restrict__ x,
                   const int* __restrict__ rowptr, const int2* __restrict__ packed,
                   float* __restrict__ outf, unsigned short* __restrict__ outb,
                   int N, int ldx, int ldo, int coff, int ldd)
{
    const int rpb = 256 / TPR;
    const int r = blockIdx.x * rpb + threadIdx.x / TPR;
    const int lane = threadIdx.x % TPR;
    if (r >= N) return;
    const int beg = rowptr[r], end = rowptr[r + 1];
    const unsigned short* xp = x + lane * 8;
    float a0[8] = {0, 0, 0, 0, 0, 0, 0, 0};
    float a1[8] = {0, 0, 0, 0, 0, 0, 0, 0};
    int i = beg;
    for (; i + 3 < end; i += 4) {
        int2 e0 = packed[i], e1 = packed[i + 1], e2 = packed[i + 2], e3 = packed[i + 3];
        uint4 v0 = *(const uint4*)&xp[(size_t)e0.x * ldx];
        uint4 v1 = *(const uint4*)&xp[(size_t)e1.x * ldx];
        uint4 v2 = *(const uint4*)&xp[(size_t)e2.x * ldx];
        uint4 v3 = *(const uint4*)&xp[(size_t)e3.x * ldx];
        float w0 = __int_as_float(e0.y), w1 = __int_as_float(e1.y);
        float w2 = __int_as_float(e2.y), w3 = __int_as_float(e3.y);
        unsigned int s0[4] = {v0.x, v0.y, v0.z, v0.w};
        unsigned int s1[4] = {v1.x, v1.y, v1.z, v1.w};
        unsigned int s2[4] = {v2.x, v2.y, v2.z, v2.w};
        unsigned int s3[4] = {v3.x, v3.y, v3.z, v3.w};
#pragma unroll
        for (int j = 0; j < 4; ++j) {
            a0[2 * j]     = fmaf(w0, __uint_as_float(s0[j] << 16),         a0[2 * j]);
            a0[2 * j + 1] = fmaf(w0, __uint_as_float(s0[j] & 0xFFFF0000u), a0[2 * j + 1]);
            a1[2 * j]     = fmaf(w1, __uint_as_float(s1[j] << 16),         a1[2 * j]);
            a1[2 * j + 1] = fmaf(w1, __uint_as_float(s1[j] & 0xFFFF0000u), a1[2 * j + 1]);
            a0[2 * j]     = fmaf(w2, __uint_as_float(s2[j] << 16),         a0[2 * j]);
            a0[2 * j + 1] = fmaf(w2, __uint_as_float(s2[j] & 0xFFFF0000u), a0[2 * j + 1]);
            a1[2 * j]     = fmaf(w3, __uint_as_float(s3[j] << 16),         a1[2 * j]);
            a1[2 * j + 1] = fmaf(w3, __uint_as_float(s3[j] & 0xFFFF0000u), a1[2 * j + 1]);
        }
    }
    for (; i + 1 < end; i += 2) {
        int2 e0 = packed[i], e1 = packed[i + 1];
        uint4 v0 = *(const uint4*)&xp[(size_t)e0.x * ldx];
        uint4 v1 = *(const uint4*)&xp[(size_t)e1.x * ldx];
        float w0 = __int_as_float(e0.y), w1 = __int_as_float(e1.y);
        unsigned int s0[4] = {v0.x, v0.y, v0.z, v0.w};
        unsigned int s1[4] = {v1.x, v1.y, v1.z, v1.w};
#pragma unroll
        for (int j = 0; j < 4; ++j) {
            a0[2 * j]     = fmaf(w0, __uint_as_float(s0[j] << 16),         a0[2 * j]);
            a0[2 * j + 1] = fmaf(w0, __uint_as_float(s0[j] & 0xFFFF0000u), a0[2 * j + 1]);
            a1[2 * j]     = fmaf(w1, __uint_as_float(s1[j] << 16),         a1[2 * j]);
            a1[2 * j + 1] = fmaf(w1, __uint_as_float(s1[j] & 0xFFFF0000u), a1[2 * j + 1]);
        }
    }
    if (i < end) {
        int2 e0 = packed[i];
        uint4 v0 = *(const uint4*)&xp[(size_t)e0.x * ldx];
        float w0 = __int_as_float(e0.y);
        unsigned int s0[4] = {v0.x, v0.y, v0.z, v0.w};
#pragma unroll
        for (int j = 0; j < 4; ++j) {
            a0[2 * j]     = fmaf(w0, __uint_as_float(s0[j] << 16),         a0[2 * j]);
            a0[2 * j + 1] = fmaf(w0, __uint_as_float(s0[j] & 0xFFFF0000u), a0[2 * j + 1]);
        }
    }
    float acc[8];
#pragma unroll
    for (int j = 0; j < 8; ++j) {
        acc[j] = a0[j] + a1[j];
        if (RELU) acc[j] = fmaxf(acc[j], 0.f);
    }
    float* o = &outf[(size_t)r * ldo + coff + lane * 8];
    *(float4*)o       = make_float4(acc[0], acc[1], acc[2], acc[3]);
    *(float4*)(o + 4) = make_float4(acc[4], acc[5], acc[6], acc[7]);
    if (DUAL) {
        uint4 p;
        p.x = pack2(acc[0], acc[1]); p.y = pack2(acc[2], acc[3]);
        p.z = pack2(acc[4], acc[5]); p.w = pack2(acc[6], acc[7]);
        *(uint4*)&outb[(size_t)r * ldd + lane * 8] = p;
    }
}

// ---------------- launch ------------------------------------------------------
extern "C" void kernel_launch(void* const* d_in, const int* in_sizes, int n_in,
                              void* d_out, int out_size, void* d_ws, size_t ws_size,
                              hipStream_t stream)
{
    const float* X    = (const float*)d_in[0];
    const int*   esrc = (const int*)  d_in[1];
    const int*   edst = (const int*)  d_in[2];
    const float* ew   = (const float*)d_in[3];
    const float* W1   = (const float*)d_in[4];
    const float* W2   = (const float*)d_in[5];
    const float* mw1  = (const float*)d_in[6];
    const float* mb1  = (const float*)d_in[7];
    const float* mw2  = (const float*)d_in[8];
    const float* mb2  = (const float*)d_in[9];

    const int IN_F = 256, HID_F = 256, OUT_F = 128;
    const int N  = in_sizes[0] / IN_F;
    const int E  = in_sizes[1];
    const int LD = OUT_F + HID_F + OUT_F;       // 512
    const int Mp = (N + 127) & ~127;

    float* out = (float*)d_out;

    // workspace (shorts)
    unsigned short* S1Y1  = (unsigned short*)d_ws;          // [Mp][512]: S1 | Y1
    unsigned short* Xb    = S1Y1 + (size_t)Mp * 512;        // [Mp][256] X bf16
    unsigned short* gb    = Xb   + (size_t)Mp * 256;        // [Mp][128]
    unsigned short* warena = gb  + (size_t)Mp * 128;        // [768][256]
    unsigned short* Wc   = warena;                          // [512][256]
    unsigned short* mw2t = warena + 512 * 256;              // [128][256]
    unsigned short* w2t  = warena + 640 * 256;              // [128][256]
    int* rowptr = (int*)(warena + 768 * 256);               // N+1
    int* bsum   = rowptr + (((N + 1) + 3) & ~3);            // 256
    int* pos    = bsum + 256;                               // N
    int2* packed = (int2*)(pos + ((N + 1) & ~1));           // E

    dim3 blk(256);
    const int nb = (N + 255) / 256;         // 196 (<=256 for scan_bsum)
    const int mT = Mp / 128;                // 391
    const int He = (E + 255) / 256;         // hist/scatter blocks: 3125

    // prep: weight conversion + rowptr zeroing + X fp32->bf16
    prep_kernel<<<768 + Mp / 8, blk, 0, stream>>>(
        mw1, W1, mw2, W2, warena, rowptr, N + 1, X, Xb, N, Mp);

    // fused gemmA + hist:
    // gemmA: [S1 | Y1] = X @ [mw1 | W1]  (relu+b1 on first 256 cols) -> bf16
    {
        const int G = mT * 4;
        int grid = 3 * G + ((He > 2 * G) ? (He - 2 * G) : 0);
        gemmA_hist<<<grid, blk, 0, stream>>>(
            Xb, Wc, mb1, S1Y1, N, G, edst, rowptr, E);
    }

    // CSR scans
    reduce_chunks<<<nb, blk, 0, stream>>>(rowptr, bsum, N);
    scan_bsum<<<1, blk, 0, stream>>>(bsum, nb, rowptr, N);
    scan_write<<<nb, blk, 0, stream>>>(rowptr, bsum, rowptr, pos, N);

    // fused K2 + scatter: out[:,0:128] = S1 @ mw2 + b2 (fp32); packed CSR edges
    {
        const int G = mT;
        int grid = 9 * G + ((He > 8 * G) ? (He - 8 * G) : 0);
        k2_scatter<<<grid, blk, 0, stream>>>(
            S1Y1, mw2t, mb2, out, N, LD, G, esrc, edst, ew, pos, packed, E);
    }

    // SpMM1: h1 = relu(A @ Y1) -> out[:,128:384] fp32 only (no bf16 copy)
    spmm_csr_bf16<32, true, false><<<(N + 7) / 8, blk, 0, stream>>>(
        S1Y1 + 256, rowptr, packed, out, nullptr, N, 512, LD, OUT_F, 0);

    // K4: gb = h1 @ W2 (bf16), A read as fp32 from out h1 slice (L3-warm)
    gemm_k4<<<mT, blk, 0, stream>>>(out + OUT_F, w2t, gb, N, LD, 128);

    // SpMM2: out[:,384:512] = A @ g (fp32)
    spmm_csr_bf16<16, false, false><<<(N + 15) / 16, blk, 0, stream>>>(
        gb, rowptr, packed, out, nullptr, N, 128, LD, OUT_F + HID_F, 0);
}